// Round 3
// baseline (15.629 us; speedup 1.0000x reference)
//
#include <hip/hip_runtime.h>

// out[b,i,d] = 31 * sum_n tgt[b,i,n,d]   (softmax column-sums == 1, F-1 = 31)
// tgt [16, 32, 64, 512] fp32 -> out [16, 32, 512] fp32. 67 MB read, 1 MB write.
//
// R2: wave-contiguous loads. Block = (row, col-half): 64 float4 cols x 64 n.
// Each wave's 64 lanes read 64 consecutive float4 = one aligned 1 KB segment
// per VMEM instruction (R1 split each instr into two 512 B segments).
// 16-deep ILP per thread, occupancy 4 waves/SIMD.

__global__ __launch_bounds__(256, 4) void rffr_colsum_kernel(
    const float4* __restrict__ tgt, float4* __restrict__ out) {
    const int bid  = blockIdx.x;          // 0..1023
    const int row  = bid >> 1;            // (b*F+f), 0..511
    const int half = bid & 1;             // column half (64 float4 each)
    const int tid  = threadIdx.x;         // 0..255
    const int c    = tid & 63;            // col within half
    const int g    = tid >> 6;            // n-group 0..3

    // row stride = 64*128 float4; n stride = 128 float4.
    const float4* base = tgt + (size_t)row * 64 * 128
                             + (size_t)g * 128
                             + (size_t)half * 64 + c;

    float4 acc = make_float4(0.f, 0.f, 0.f, 0.f);
#pragma unroll
    for (int k = 0; k < 16; ++k) {        // n = g + 4k
        float4 v = base[(size_t)k * 4 * 128];
        acc.x += v.x; acc.y += v.y; acc.z += v.z; acc.w += v.w;
    }

    __shared__ float4 part[256];
    part[tid] = acc;
    __syncthreads();
    if (tid < 128) {                      // fold g=2,3 into g=0,1
        float4 o = part[tid + 128];
        acc.x += o.x; acc.y += o.y; acc.z += o.z; acc.w += o.w;
        part[tid] = acc;
    }
    __syncthreads();
    if (tid < 64) {                       // fold g=1 into g=0, scale, store
        float4 o = part[tid + 64];
        float4 r;
        r.x = 31.0f * (acc.x + o.x);
        r.y = 31.0f * (acc.y + o.y);
        r.z = 31.0f * (acc.z + o.z);
        r.w = 31.0f * (acc.w + o.w);
        out[(size_t)row * 128 + (size_t)half * 64 + tid] = r;
    }
}

extern "C" void kernel_launch(void* const* d_in, const int* in_sizes, int n_in,
                              void* d_out, int out_size, void* d_ws, size_t ws_size,
                              hipStream_t stream) {
    const float4* tgt = (const float4*)d_in[0];
    float4* out = (float4*)d_out;
    rffr_colsum_kernel<<<dim3(1024), dim3(256), 0, stream>>>(tgt, out);
}

// Round 5
// 13.790 us; speedup vs baseline: 1.1333x; 1.1333x over previous
//
#include <hip/hip_runtime.h>

// out[b,i,d] = 31 * sum_n tgt[b,i,n,d]   (softmax column-sums == 1, F-1 = 31)
// tgt [16, 32, 64, 512] fp32 -> out [16, 32, 512] fp32. 67 MB read, 1 MB write.
//
// R4 = R3 probe with build fix: __builtin_nontemporal_load needs a native
// clang vector type, not HIP_vector_type<float,4>. Pure streaming kernel,
// zero reduction structure: 1 thread = 1 output float4 column, 64-deep sum.
// No LDS, no __syncthreads. NT loads (67 MB input, 2x L2, zero reuse).

typedef float f32x4 __attribute__((ext_vector_type(4)));

__global__ __launch_bounds__(256) void rffr_colsum_kernel(
    const f32x4* __restrict__ tgt, f32x4* __restrict__ out) {
    const int bid = blockIdx.x;               // 0..255 -> 2 rows each
    const int tid = threadIdx.x;              // 0..255
    const int row = (bid << 1) | (tid >> 7);  // 0..511
    const int col = tid & 127;                // float4 column

    const f32x4* base = tgt + (size_t)row * 64 * 128 + col;

    f32x4 a0 = (f32x4)(0.f);
    f32x4 a1 = (f32x4)(0.f);
#pragma unroll 8
    for (int k = 0; k < 32; ++k) {
        f32x4 v0 = __builtin_nontemporal_load(base + (size_t)(2 * k) * 128);
        f32x4 v1 = __builtin_nontemporal_load(base + (size_t)(2 * k + 1) * 128);
        a0 += v0;
        a1 += v1;
    }

    f32x4 r = 31.0f * (a0 + a1);
    __builtin_nontemporal_store(r, out + (size_t)row * 128 + col);
}

extern "C" void kernel_launch(void* const* d_in, const int* in_sizes, int n_in,
                              void* d_out, int out_size, void* d_ws, size_t ws_size,
                              hipStream_t stream) {
    const f32x4* tgt = (const f32x4*)d_in[0];
    f32x4* out = (f32x4*)d_out;
    rffr_colsum_kernel<<<dim3(256), dim3(256), 0, stream>>>(tgt, out);
}